// Round 2
// baseline (222.980 us; speedup 1.0000x reference)
//
#include <hip/hip_runtime.h>

// Problem constants (match reference)
#define BB 32
#define SS 64
#define TT 512
#define VV 50257
#define DD 128
#define NC 16   // chunks per row
#define CL 32   // chunk length (NC*CL == TT)

// ws layout (floats):
//   P    [BB][TT+1][DD]  = 32*513*128 = 2,101,248 floats (8.4 MB)
//   Csum [BB][NC][DD]    = 32*16*128  =    65,536 floats (0.26 MB)
#define P_ELEMS (BB * (TT + 1) * DD)

// Kernel 1: per-chunk sums of gathered W rows (no dedup).
__global__ __launch_bounds__(DD) void chunksum_kernel(const int* __restrict__ tok,
                                                      const float* __restrict__ W,
                                                      float* __restrict__ Csum) {
    const int bc = blockIdx.x;          // b*NC + c
    const int b  = bc >> 4;
    const int c  = bc & (NC - 1);
    const int d  = threadIdx.x;

    __shared__ int tokS[CL];
    if (d < CL) tokS[d] = tok[b * TT + c * CL + d];
    __syncthreads();

    float acc = 0.f;
#pragma unroll 8
    for (int t = 0; t < CL; ++t)
        acc += W[(size_t)tokS[t] * DD + d];

    Csum[(size_t)bc * DD + d] = acc;
}

// Kernel 2: per-chunk inclusive scan, offset by exclusive sum of prior chunks.
__global__ __launch_bounds__(DD) void scan_kernel(const int* __restrict__ tok,
                                                  const float* __restrict__ W,
                                                  const float* __restrict__ Csum,
                                                  float* __restrict__ P) {
    const int bc = blockIdx.x;
    const int b  = bc >> 4;
    const int c  = bc & (NC - 1);
    const int d  = threadIdx.x;

    __shared__ int tokS[CL];
    if (d < CL) tokS[d] = tok[b * TT + c * CL + d];
    __syncthreads();

    float acc = 0.f;
    for (int cc = 0; cc < c; ++cc)
        acc += Csum[((size_t)b * NC + cc) * DD + d];

    float* Pb = P + (size_t)b * (TT + 1) * DD;
    if (c == 0) Pb[d] = 0.f;            // P[b][0][:] = 0

    const int base = c * CL;
#pragma unroll 4
    for (int t = 0; t < CL; ++t) {
        acc += W[(size_t)tokS[t] * DD + d];
        Pb[(size_t)(base + t + 1) * DD + d] = acc;
    }
}

// Kernel 3: out[b,s] = P[j] - P[i] + bias - sum of in-span duplicate W rows.
__global__ __launch_bounds__(DD) void out_kernel(const int* __restrict__ tok,
                                                 const int* __restrict__ spans,
                                                 const float* __restrict__ W,
                                                 const float* __restrict__ bias,
                                                 const float* __restrict__ P,
                                                 float* __restrict__ out) {
    const int bs = blockIdx.x;          // b*SS + s
    const int b  = bs >> 6;
    const int d  = threadIdx.x;

    const int i = spans[bs * 2 + 0];
    const int j = spans[bs * 2 + 1];
    const int L = j - i;

    __shared__ int tokS[TT];
    __shared__ int dup[TT];
    __shared__ int ndup;
    if (d == 0) ndup = 0;
    for (int t = d; t < L; t += DD)
        tokS[t] = tok[b * TT + i + t];
    __syncthreads();

    // Position t is a duplicate iff its token occurs earlier IN the span.
    for (int t = d; t < L; t += DD) {
        const int v = tokS[t];
        for (int u = t - 1; u >= 0; --u) {
            if (tokS[u] == v) {
                const int k = atomicAdd(&ndup, 1);
                dup[k] = v;
                break;
            }
        }
    }
    __syncthreads();

    const float* Pb = P + (size_t)b * (TT + 1) * DD;
    float r = Pb[(size_t)j * DD + d] - Pb[(size_t)i * DD + d] + bias[d];

    const int n = ndup;
    for (int k = 0; k < n; ++k)
        r -= W[(size_t)dup[k] * DD + d];

    out[(size_t)bs * DD + d] = r;
}

extern "C" void kernel_launch(void* const* d_in, const int* in_sizes, int n_in,
                              void* d_out, int out_size, void* d_ws, size_t ws_size,
                              hipStream_t stream) {
    const int*   word_encs = (const int*)  d_in[0];   // (B,T) int32
    const int*   span_idxs = (const int*)  d_in[1];   // (B,S,2) int32
    const float* W         = (const float*)d_in[2];   // (V,D) f32
    const float* bias      = (const float*)d_in[3];   // (D,) f32
    float*       out       = (float*)      d_out;     // (B,S,D) f32

    float* P    = (float*)d_ws;
    float* Csum = P + P_ELEMS;

    chunksum_kernel<<<BB * NC, DD, 0, stream>>>(word_encs, W, Csum);
    scan_kernel    <<<BB * NC, DD, 0, stream>>>(word_encs, W, Csum, P);
    out_kernel     <<<BB * SS, DD, 0, stream>>>(word_encs, span_idxs, W, bias, P, out);
}

// Round 3
// 105.866 us; speedup vs baseline: 2.1062x; 2.1062x over previous
//
#include <hip/hip_runtime.h>

// Problem constants (match reference)
#define BB 32
#define SS 64
#define TT 512
#define VV 50257
#define DD 128
#define NC 16   // chunks per row
#define CL 32   // chunk length (NC*CL == TT)

// ws layout (floats/ints):
//   P    [BB][TT+1][DD] f32 = 2,101,248 floats (8.4 MB)
//   Csum [BB][NC][DD]   f32 =    65,536 floats (0.26 MB)
//   prev [BB][TT]       i32 =    16,384 ints   (64 KB)
#define P_ELEMS    (BB * (TT + 1) * DD)
#define CSUM_ELEMS (BB * NC * DD)

// Kernel 1: prev[b,t] = nearest t' < t with same token, else -1.
// Forward int4 LDS scan keeping the LAST match -> nearest previous occurrence.
// 128 independent vector LDS reads worst-case (pipelineable), no dependent chain.
__global__ __launch_bounds__(TT) void prev_kernel(const int* __restrict__ tok,
                                                  int* __restrict__ prev) {
    const int b = blockIdx.x;
    const int t = threadIdx.x;
    __shared__ alignas(16) int row[TT];
    row[t] = tok[b * TT + t];
    __syncthreads();

    const int v = row[t];
    const int4* rowv = reinterpret_cast<const int4*>(row);
    int p = -1;
    const int n4 = (t + 3) >> 2;           // int4 blocks covering [0, t)
    for (int u4 = 0; u4 < n4; ++u4) {
        const int4 q = rowv[u4];           // broadcast across lanes (same u4)
        const int base = u4 << 2;
        if (base + 0 < t && q.x == v) p = base + 0;
        if (base + 1 < t && q.y == v) p = base + 1;
        if (base + 2 < t && q.z == v) p = base + 2;
        if (base + 3 < t && q.w == v) p = base + 3;
    }
    prev[b * TT + t] = p;
}

// Kernel 2: per-chunk sums of gathered W rows (no dedup).
__global__ __launch_bounds__(DD) void chunksum_kernel(const int* __restrict__ tok,
                                                      const float* __restrict__ W,
                                                      float* __restrict__ Csum) {
    const int bc = blockIdx.x;          // b*NC + c
    const int b  = bc >> 4;
    const int c  = bc & (NC - 1);
    const int d  = threadIdx.x;

    __shared__ int tokS[CL];
    if (d < CL) tokS[d] = tok[b * TT + c * CL + d];
    __syncthreads();

    float acc = 0.f;
#pragma unroll 8
    for (int t = 0; t < CL; ++t)
        acc += W[(size_t)tokS[t] * DD + d];

    Csum[(size_t)bc * DD + d] = acc;
}

// Kernel 3: per-chunk inclusive scan, offset by exclusive sum of prior chunks.
__global__ __launch_bounds__(DD) void scan_kernel(const int* __restrict__ tok,
                                                  const float* __restrict__ W,
                                                  const float* __restrict__ Csum,
                                                  float* __restrict__ P) {
    const int bc = blockIdx.x;
    const int b  = bc >> 4;
    const int c  = bc & (NC - 1);
    const int d  = threadIdx.x;

    __shared__ int tokS[CL];
    if (d < CL) tokS[d] = tok[b * TT + c * CL + d];
    __syncthreads();

    float acc = 0.f;
    for (int cc = 0; cc < c; ++cc)
        acc += Csum[((size_t)b * NC + cc) * DD + d];

    float* Pb = P + (size_t)b * (TT + 1) * DD;
    if (c == 0) Pb[d] = 0.f;            // P[b][0][:] = 0

    const int base = c * CL;
#pragma unroll 4
    for (int t = 0; t < CL; ++t) {
        acc += W[(size_t)tokS[t] * DD + d];
        Pb[(size_t)(base + t + 1) * DD + d] = acc;
    }
}

// Kernel 4: out[b,s] = P[j] - P[i] + bias - sum of in-span duplicate W rows.
// Duplicate predicate is O(L) coalesced: prev[b,t] >= i.
__global__ __launch_bounds__(DD) void out_kernel(const int* __restrict__ tok,
                                                 const int* __restrict__ prevA,
                                                 const int* __restrict__ spans,
                                                 const float* __restrict__ W,
                                                 const float* __restrict__ bias,
                                                 const float* __restrict__ P,
                                                 float* __restrict__ out) {
    const int bs = blockIdx.x;          // b*SS + s
    const int b  = bs >> 6;
    const int d  = threadIdx.x;

    const int i = spans[bs * 2 + 0];
    const int j = spans[bs * 2 + 1];

    __shared__ int dup[TT];
    __shared__ int ndup;
    if (d == 0) ndup = 0;
    __syncthreads();

    // Position t duplicates an earlier in-span token iff nearest prev >= i.
    for (int t = i + d; t < j; t += DD) {
        if (prevA[b * TT + t] >= i) {
            const int k = atomicAdd(&ndup, 1);
            dup[k] = tok[b * TT + t];
        }
    }
    __syncthreads();

    const float* Pb = P + (size_t)b * (TT + 1) * DD;
    float r = Pb[(size_t)j * DD + d] - Pb[(size_t)i * DD + d] + bias[d];

    const int n = ndup;
    for (int k = 0; k < n; ++k)
        r -= W[(size_t)dup[k] * DD + d];

    out[(size_t)bs * DD + d] = r;
}

extern "C" void kernel_launch(void* const* d_in, const int* in_sizes, int n_in,
                              void* d_out, int out_size, void* d_ws, size_t ws_size,
                              hipStream_t stream) {
    const int*   word_encs = (const int*)  d_in[0];   // (B,T) int32
    const int*   span_idxs = (const int*)  d_in[1];   // (B,S,2) int32
    const float* W         = (const float*)d_in[2];   // (V,D) f32
    const float* bias      = (const float*)d_in[3];   // (D,) f32
    float*       out       = (float*)      d_out;     // (B,S,D) f32

    float* P    = (float*)d_ws;
    float* Csum = P + P_ELEMS;
    int*   prev = (int*)(Csum + CSUM_ELEMS);

    prev_kernel    <<<BB,      TT, 0, stream>>>(word_encs, prev);
    chunksum_kernel<<<BB * NC, DD, 0, stream>>>(word_encs, W, Csum);
    scan_kernel    <<<BB * NC, DD, 0, stream>>>(word_encs, W, Csum, P);
    out_kernel     <<<BB * SS, DD, 0, stream>>>(word_encs, prev, span_idxs, W, bias, P, out);
}

// Round 5
// 96.553 us; speedup vs baseline: 2.3094x; 1.0965x over previous
//
#include <hip/hip_runtime.h>

// Problem constants (match reference)
#define BB 32
#define SS 64
#define TT 512
#define VV 50257
#define DD 128

#define DSLICES 4
#define DW (DD / DSLICES)        // 32 dims per block
#define NCH 32                   // chunk groups per block
#define CHL (TT / NCH)           // 16 tokens per chunk
#define NTHREADS (NCH * DW)      // 1024
#define NSLOT (TT / 4 + 2)       // 130 >= 129 max distinct boundaries

// One block per (row b, d-slice). Everything lives in LDS:
//  - boundary-compacted prefix table PB[slot][d]  (out needs P only at span ends)
//  - dup list: positions whose token occurred earlier in the row (E[count]~2.6)
// out[b,s,d] = PB[slot[j]] - PB[slot[i]] + bias - sum of in-span dup W rows.
__global__ __launch_bounds__(NTHREADS) void fused_bow(
    const int* __restrict__ tok,     // (B,T)
    const int* __restrict__ spans,   // (B,S,2)
    const float* __restrict__ W,     // (V,D)
    const float* __restrict__ bias,  // (D)
    float* __restrict__ out)         // (B,S,D)
{
    const int b     = blockIdx.x >> 2;
    const int dbase = (blockIdx.x & 3) * DW;
    const int tid   = threadIdx.x;
    const int c     = tid >> 5;        // chunk group 0..31
    const int d     = tid & (DW - 1);  // dim 0..31

    __shared__ alignas(16) int tokS[TT];          // 2 KB
    __shared__ int spanI[SS], spanJ[SS];          // 512 B
    __shared__ unsigned char isB[TT + 1];         // 513 B
    __shared__ int flagScan[TT + 1];              // 2 KB (scan workspace)
    __shared__ short slot[TT + 1];                // 1 KB
    __shared__ float csum[NCH][DW];               // 4 KB
    __shared__ int dupT[TT], dupP[TT], dupV[TT];  // 6 KB
    __shared__ int ndup;
    __shared__ float PB[NSLOT][DW];               // 16.6 KB

    // ---- Phase 0: stage tokens, spans; clear flags ----
    if (tid < TT) tokS[tid] = tok[b * TT + tid];
    if (tid < SS) {
        spanI[tid] = spans[(b * SS + tid) * 2 + 0];
        spanJ[tid] = spans[(b * SS + tid) * 2 + 1];
    }
    if (tid <= TT) { isB[tid] = 0; flagScan[tid] = 0; }
    if (tid == 0) ndup = 0;
    __syncthreads();

    // ---- Phase 1: mark boundary positions (benign 1-races) ----
    if (tid < SS) {
        isB[spanI[tid]] = 1;  flagScan[spanI[tid]] = 1;
        isB[spanJ[tid]] = 1;  flagScan[spanJ[tid]] = 1;
    }
    __syncthreads();

    // ---- Phase 2: Hillis-Steele inclusive scan over 513 flags -> slot (exclusive) ----
    const int myflag = (tid <= TT) ? flagScan[tid] : 0;
    for (int off = 1; off <= TT; off <<= 1) {
        int v = 0;
        if (tid <= TT && tid >= off) v = flagScan[tid - off];
        __syncthreads();
        if (tid <= TT) flagScan[tid] += v;
        __syncthreads();
    }
    if (tid <= TT) slot[tid] = (short)(flagScan[tid] - myflag);

    // ---- Phase 3: prev-scan (nearest earlier same token) + dup compaction ----
    if (tid < TT) {
        const int t = tid, v = tokS[t];
        const int4* rowv = reinterpret_cast<const int4*>(tokS);
        int p = -1;
        const int n4 = (t + 3) >> 2;      // int4 blocks covering [0, t)
        for (int u4 = 0; u4 < n4; ++u4) {
            const int4 q = rowv[u4];      // forward scan keeps LAST match = nearest prev
            const int base = u4 << 2;
            if (base + 0 < t && q.x == v) p = base + 0;
            if (base + 1 < t && q.y == v) p = base + 1;
            if (base + 2 < t && q.z == v) p = base + 2;
            if (base + 3 < t && q.w == v) p = base + 3;
        }
        if (p >= 0) {
            const int k = atomicAdd(&ndup, 1);
            dupT[k] = t; dupP[k] = p; dupV[k] = v;
        }
    }

    // ---- Phase 4: pass-1 chunk sums (gather W, 16-long chains) ----
    const float* Wd = W + dbase;
    const int tbase = c * CHL;
    float acc = 0.f;
#pragma unroll
    for (int t = 0; t < CHL; ++t)
        acc += Wd[(size_t)tokS[tbase + t] * DD + d];
    csum[c][d] = acc;
    __syncthreads();

    // ---- Phase 5: chunk offset (register), P[0] slot if needed ----
    float off = 0.f;
    for (int cc = 0; cc < c; ++cc) off += csum[cc][d];
    if (tid < DW && isB[0]) PB[0][tid] = 0.f;   // slot[0]==0 when flagged

    // ---- Phase 6: pass-2 running prefix (L1-hot re-gather), store at boundaries ----
    acc = off;
#pragma unroll
    for (int t = 0; t < CHL; ++t) {
        acc += Wd[(size_t)tokS[tbase + t] * DD + d];
        const int p = tbase + t + 1;
        if (isB[p]) PB[slot[p]][d] = acc;
    }
    __syncthreads();

    // ---- Phase 7: span outputs straight from LDS ----
    const int nd = ndup;
    const float bv = bias[dbase + d];
    for (int s = c; s < SS; s += NCH) {
        const int i = spanI[s], j = spanJ[s];
        float r = PB[slot[j]][d] - PB[slot[i]][d] + bv;
        for (int k = 0; k < nd; ++k) {
            // t in [i,j) with nearest-prev also >= i  => in-span duplicate
            if (dupT[k] < j && dupP[k] >= i)
                r -= Wd[(size_t)dupV[k] * DD + d];
        }
        out[(size_t)(b * SS + s) * DD + dbase + d] = r;
    }
}

extern "C" void kernel_launch(void* const* d_in, const int* in_sizes, int n_in,
                              void* d_out, int out_size, void* d_ws, size_t ws_size,
                              hipStream_t stream) {
    const int*   word_encs = (const int*)  d_in[0];   // (B,T) int32
    const int*   span_idxs = (const int*)  d_in[1];   // (B,S,2) int32
    const float* W         = (const float*)d_in[2];   // (V,D) f32
    const float* bias      = (const float*)d_in[3];   // (D,) f32
    float*       out       = (float*)      d_out;     // (B,S,D) f32

    fused_bow<<<BB * DSLICES, NTHREADS, 0, stream>>>(word_encs, span_idxs, W, bias, out);
}